// Round 14
// baseline (281.189 us; speedup 1.0000x reference)
//
#include <hip/hip_runtime.h>

typedef unsigned short ushort_t;
typedef unsigned long long u64_t;
typedef __attribute__((ext_vector_type(8))) short v8bf;
typedef __attribute__((ext_vector_type(8))) unsigned short v8us;
typedef __attribute__((ext_vector_type(4))) float v4f;

#define BROWS 4096
#define DIMK 256
#define QN 32768
#define EXPSCALE 14.426950408889634f   // 10 * log2(e)

__device__ __forceinline__ ushort_t f2bf(float f) {
    unsigned u = __float_as_uint(f);
    return (ushort_t)((u + 0x7FFFu + ((u >> 16) & 1u)) >> 16);   // RNE
}
__device__ __forceinline__ u64_t shfl_xor_u64(u64_t v, int off) {
    unsigned lo = (unsigned)(v & 0xFFFFFFFFull);
    unsigned hi = (unsigned)(v >> 32);
    lo = (unsigned)__shfl_xor((int)lo, off, 64);
    hi = (unsigned)__shfl_xor((int)hi, off, 64);
    return ((u64_t)hi << 32) | (u64_t)lo;
}
#define GLOAD(g, l_) __builtin_amdgcn_global_load_lds(                         \
    (const __attribute__((address_space(1))) void*)(g),                        \
    (__attribute__((address_space(3))) void*)(l_), 16, 0, 0)

// ---- bf16 conversion of the queue ----
__global__ __launch_bounds__(256) void conv_bf16(const float* __restrict__ in,
                                                 ushort_t* __restrict__ out) {
    const size_t i = ((size_t)blockIdx.x * 256 + threadIdx.x) * 8;
    float4 x = *(const float4*)&in[i];
    float4 y = *(const float4*)&in[i + 4];
    v8us o;
    o[0] = f2bf(x.x); o[1] = f2bf(x.y); o[2] = f2bf(x.z); o[3] = f2bf(x.w);
    o[4] = f2bf(y.x); o[5] = f2bf(y.y); o[6] = f2bf(y.z); o[7] = f2bf(y.w);
    *(v8us*)&out[i] = o;
}

// ---- fused two-layer projection + L2 norm (16 rows/block, grid.y = f1/f2) ----
__global__ __launch_bounds__(256) void proj_fused(const float* __restrict__ F1,
                                                  const float* __restrict__ F2,
                                                  const float* __restrict__ W1,
                                                  const float* __restrict__ b1,
                                                  const float* __restrict__ W2,
                                                  const float* __restrict__ b2,
                                                  ushort_t* __restrict__ P) {
    __shared__ float fr[16][256];
    __shared__ float hr[16][256];
    __shared__ float partial[4][16];
    const float* F = blockIdx.y ? F2 : F1;
    ushort_t* Po = P + (size_t)blockIdx.y * BROWS * DIMK;
    const int r0 = blockIdx.x << 4, j = threadIdx.x;
    const int w = j >> 6, l = j & 63;
#pragma unroll
    for (int r = 0; r < 16; ++r) fr[r][j] = F[(size_t)(r0 + r) * DIMK + j];
    __syncthreads();
    float acc[16];
    {
        const float bj = b1[j];
#pragma unroll
        for (int r = 0; r < 16; ++r) acc[r] = bj;
        for (int k = 0; k < DIMK; k += 4) {
            const float w0 = W1[(k + 0) * DIMK + j];
            const float w1 = W1[(k + 1) * DIMK + j];
            const float w2 = W1[(k + 2) * DIMK + j];
            const float w3 = W1[(k + 3) * DIMK + j];
#pragma unroll
            for (int r = 0; r < 16; ++r) {
                float4 f = *(const float4*)&fr[r][k];
                acc[r] = fmaf(f.x, w0, acc[r]);
                acc[r] = fmaf(f.y, w1, acc[r]);
                acc[r] = fmaf(f.z, w2, acc[r]);
                acc[r] = fmaf(f.w, w3, acc[r]);
            }
        }
#pragma unroll
        for (int r = 0; r < 16; ++r) hr[r][j] = acc[r] > 0.f ? acc[r] : 0.f;
    }
    __syncthreads();
    {
        const float bj = b2[j];
#pragma unroll
        for (int r = 0; r < 16; ++r) acc[r] = bj;
        for (int k = 0; k < DIMK; k += 4) {
            const float w0 = W2[(k + 0) * DIMK + j];
            const float w1 = W2[(k + 1) * DIMK + j];
            const float w2 = W2[(k + 2) * DIMK + j];
            const float w3 = W2[(k + 3) * DIMK + j];
#pragma unroll
            for (int r = 0; r < 16; ++r) {
                float4 f = *(const float4*)&hr[r][k];
                acc[r] = fmaf(f.x, w0, acc[r]);
                acc[r] = fmaf(f.y, w1, acc[r]);
                acc[r] = fmaf(f.z, w2, acc[r]);
                acc[r] = fmaf(f.w, w3, acc[r]);
            }
        }
    }
#pragma unroll
    for (int r = 0; r < 16; ++r) {
        float s = acc[r] * acc[r];
        s += __shfl_xor(s, 1);  s += __shfl_xor(s, 2);
        s += __shfl_xor(s, 4);  s += __shfl_xor(s, 8);
        s += __shfl_xor(s, 16); s += __shfl_xor(s, 32);
        if (l == 0) partial[w][r] = s;
    }
    __syncthreads();
#pragma unroll
    for (int r = 0; r < 16; ++r) {
        const float tot = partial[0][r] + partial[1][r] + partial[2][r] + partial[3][r];
        const float inv = 1.f / fmaxf(sqrtf(tot), 1e-12f);
        Po[(size_t)(r0 + r) * DIMK + j] = f2bf(acc[r] * inv);
    }
}

// ---- stage a 128-row x 256-k bf16 panel into 64KB LDS (512 threads, 8/thread).
// Global source pre-swizzled: 16B slot s of row r holds octet (s&~7)|((s&7)^(r&7)).
__device__ __forceinline__ void stage_panel(const ushort_t* __restrict__ M, int grow0,
                                            ushort_t* lds, int w, int l) {
#pragma unroll
    for (int j = 0; j < 8; ++j) {
        const int seg = (j << 3) + w;              // 64 segs of 1KB
        const int row = (seg << 1) + (l >> 5);     // 512B rows
        const int s = l & 31;
        const int oct = (s & ~7) | ((s & 7) ^ (row & 7));
        GLOAD(&M[(size_t)(grow0 + row) * DIMK + (oct << 3)], lds + (seg << 9));
    }
}

// ---- stage a 512-col x 32-k B tile (32KB, 64B rows; 512 threads, 4/thread).
// Pre-swizzled source: phys 16B slot s of row r holds logical octet s ^ ((r>>1)&3).
__device__ __forceinline__ void stage_b(const ushort_t* __restrict__ B, int col0,
                                        int kelem, ushort_t* dst, int w, int l) {
#pragma unroll
    for (int j = 0; j < 4; ++j) {
        const int seg = (j << 3) + w;                 // 32 segs of 1KB (16 rows)
        const int row = (seg << 4) + (l >> 2);
        const int oct = (l & 3) ^ ((l >> 3) & 3);     // == (l&3) ^ ((row>>1)&3)
        GLOAD(&B[(size_t)(col0 + row) * DIMK + kelem + (oct << 3)], dst + (seg << 9));
    }
}

// ---- persistent single-block-per-CU GEMM, m97 single-barrier schedule.
// 512 threads = 8 waves (2M x 4N); block tile 128 rows x 512 cols; wave tile
// 64x128 (acc 4x8 = 128 VGPR). A panel (128x256) hoisted to LDS once; B tiles
// (512x32k = 32KB) DOUBLE-buffered: phase p issues stage(p+1) -> buf[(p+1)&1],
// computes from buf[p&1], then ONE __syncthreads (own-vmcnt drain => stage
// latency hides under the ~1240cy MFMA window). LDS = 64+2x32 = 128KB -> 1
// block/CU; 8 waves co-resident cap VGPR at 256 (est ~217; spill tripwire:
// WRITE_SIZE >> KB invalidates the round, cf R12's 27MB scratch).
// MODE 0: fused argmax, 256 blocks (=CUs), NT=16; XCD-pinned L2 decode (R9).
// MODE 1: exp-sums + diag, 256 blocks, NT=2, plain-store partial strips.
template <int MODE, int NT>
__global__ __launch_bounds__(512) void nn_lse(const ushort_t* __restrict__ Abase,
                                              const ushort_t* __restrict__ Bbase,
                                              u64_t* __restrict__ packed,
                                              float* __restrict__ srp,
                                              float* __restrict__ scp,
                                              float* __restrict__ diag) {
    __shared__ __align__(16) ushort_t Alds[128 * 256];   // 64 KB, staged once
    __shared__ __align__(16) ushort_t Bs[2][512 * 32];   // 2 x 32 KB
    const int tid = threadIdx.x;
    const int w = tid >> 6, l = tid & 63;
    const int wr = w >> 2, wc = w & 3;   // 2M x 4N waves; wave tile 64x128
    constexpr int NP = NT * 8;

    int arow0, colbase, rowblk = 0, colstrip = 0, z = 0;
    const ushort_t* A; const ushort_t* B;
    u64_t* pk_out = nullptr;
    float* dg = nullptr;
    if (MODE == 0) {
        const int bid = blockIdx.x;                // 256 blocks = 1 per CU
        const int xcd = bid & 7, i = bid >> 3;     // i in 0..31
        const int half = xcd & 1;
        const int pairgrp = xcd >> 1;              // owns 8192 cols
        arow0 = i << 7;                            // 32 row-blocks of 128
        colbase = pairgrp << 13;
        A = Abase + (size_t)half * BROWS * DIMK;
        B = Bbase;
        pk_out = packed + (size_t)half * BROWS;
    } else {
        z = blockIdx.x & 1;
        const int i = blockIdx.x >> 1;             // 0..127
        rowblk = i & 31;
        colstrip = i >> 5;                         // 0..3, 1024 cols each
        arow0 = rowblk << 7;
        colbase = colstrip << 10;
        A = Abase + (size_t)z * BROWS * DIMK;
        B = Bbase + (size_t)(1 - z) * BROWS * DIMK;
        dg = diag + (size_t)z * BROWS;
    }

    // prologue: A panel + first B tile, one drain
    stage_panel(A, arow0, (ushort_t*)Alds, w, l);
    stage_b(B, colbase, 0, &Bs[0][0], w, l);
    __syncthreads();

    unsigned best[4][4];
    float rsum[4][4];
#pragma unroll
    for (int a = 0; a < 4; ++a)
#pragma unroll
        for (int r = 0; r < 4; ++r) { best[a][r] = 0u; rsum[a][r] = 0.f; }

    for (int t = 0; t < NT; ++t) {
        v4f acc[4][8];
        const float cinit = (MODE == 0) ? 2.0f : 0.0f;   // +2 -> positive, uint-monotone
#pragma unroll
        for (int a = 0; a < 4; ++a)
#pragma unroll
            for (int b = 0; b < 8; ++b) acc[a][b] = (v4f){cinit, cinit, cinit, cinit};

#pragma unroll
        for (int k0 = 0; k0 < 8; ++k0) {          // K-phases of 32
            const int p = (t << 3) + k0;
            if (p + 1 < NP) {                      // stage next phase's B tile
                const int tn = (p + 1) >> 3, kn = (p + 1) & 7;
                stage_b(B, colbase + (tn << 9), kn << 5, &Bs[(p + 1) & 1][0], w, l);
            }
            const ushort_t* bufr = &Bs[p & 1][0];
            const int lo = l >> 4;                 // 0..3
            v8bf av[4], bv[8];
#pragma unroll
            for (int mi = 0; mi < 4; ++mi) {
                const int row = (wr << 6) + (mi << 4) + (l & 15);
                const int phys = ((k0 >> 1) << 3) | ((((k0 & 1) << 2) + lo) ^ (row & 7));
                av[mi] = *(const v8bf*)&Alds[(row << 8) + (phys << 3)];
            }
#pragma unroll
            for (int nj = 0; nj < 8; ++nj) {
                const int row = (wc << 7) + (nj << 4) + (l & 15);
                const int phys = lo ^ ((row >> 1) & 3);
                bv[nj] = *(const v8bf*)&bufr[(row << 5) + (phys << 3)];
            }
#pragma unroll
            for (int mi = 0; mi < 4; ++mi)
#pragma unroll
                for (int nj = 0; nj < 8; ++nj)
                    acc[mi][nj] = __builtin_amdgcn_mfma_f32_16x16x32_bf16(
                        av[mi], bv[nj], acc[mi][nj], 0, 0, 0);
            __syncthreads();   // drains own stage(p+1); all waves done with bufr
        }

        if (MODE == 0) {
            // running argmax: (bits(v+2) & 0xFFFFFF80) | (t<<3) | nj, uint-max
#pragma unroll
            for (int mi = 0; mi < 4; ++mi)
#pragma unroll
                for (int r = 0; r < 4; ++r) {
                    unsigned m = (__float_as_uint(acc[mi][0][r]) & 0xFFFFFF80u) |
                                 ((unsigned)t << 3);
#pragma unroll
                    for (int nj = 1; nj < 8; ++nj) {
                        unsigned c = (__float_as_uint(acc[mi][nj][r]) & 0xFFFFFF80u) |
                                     ((unsigned)t << 3) | (unsigned)nj;
                        m = c > m ? c : m;
                    }
                    if (m > best[mi][r]) best[mi][r] = m;
                }
        } else {
            const int cb = colbase + (t << 9);
#pragma unroll
            for (int mi = 0; mi < 4; ++mi)
#pragma unroll
                for (int nj = 0; nj < 8; ++nj) {
                    const int gr16 = arow0 + (wr << 6) + (mi << 4);
                    const int gc16 = cb + (wc << 7) + (nj << 4);
                    if (gr16 == gc16) {
#pragma unroll
                        for (int r = 0; r < 4; ++r) {
                            const int rr = ((l >> 4) << 2) + r;
                            if ((l & 15) == rr) dg[gr16 + rr] = acc[mi][nj][r] * 10.0f;
                        }
                    }
                }
#pragma unroll
            for (int mi = 0; mi < 4; ++mi)
#pragma unroll
                for (int nj = 0; nj < 8; ++nj) {
                    v4f tv = acc[mi][nj];
                    tv[0] = exp2f(tv[0] * EXPSCALE);
                    tv[1] = exp2f(tv[1] * EXPSCALE);
                    tv[2] = exp2f(tv[2] * EXPSCALE);
                    tv[3] = exp2f(tv[3] * EXPSCALE);
                    acc[mi][nj] = tv;
                }
#pragma unroll
            for (int mi = 0; mi < 4; ++mi)
#pragma unroll
                for (int r = 0; r < 4; ++r) {
                    float s = 0.f;
#pragma unroll
                    for (int nj = 0; nj < 8; ++nj) s += acc[mi][nj][r];
                    rsum[mi][r] += s;
                }
            // col partials: unique strip (z,rowblk,wr); plain stores
#pragma unroll
            for (int nj = 0; nj < 8; ++nj) {
                float s = 0.f;
#pragma unroll
                for (int mi = 0; mi < 4; ++mi)
#pragma unroll
                    for (int r = 0; r < 4; ++r) s += acc[mi][nj][r];
                s += __shfl_xor(s, 16); s += __shfl_xor(s, 32);
                if (l < 16)
                    scp[((size_t)(z << 6) + (rowblk << 1) + wr) * BROWS +
                        cb + (wc << 7) + (nj << 4) + l] = s;
            }
        }
    }

    if (MODE == 0) {
#pragma unroll
        for (int mi = 0; mi < 4; ++mi)
#pragma unroll
            for (int r = 0; r < 4; ++r) {
                const unsigned wb = best[mi][r];
                const unsigned col = (unsigned)(colbase + (int)(((wb >> 3) & 15u) << 9) +
                                                (wc << 7) + (int)((wb & 7u) << 4)) + (l & 15);
                u64_t pk = ((u64_t)wb << 32) | (u64_t)(0xFFFFFFFFu - col);
#pragma unroll
                for (int off = 1; off < 16; off <<= 1) {
                    u64_t o = shfl_xor_u64(pk, off);
                    if (o > pk) pk = o;
                }
                if ((l & 15) == 0)
                    atomicMax(&pk_out[arow0 + (wr << 6) + (mi << 4) + ((l >> 4) << 2) + r], pk);
            }
    } else {
        // row partials: unique strip (z, colstrip, wc); plain stores
#pragma unroll
        for (int mi = 0; mi < 4; ++mi)
#pragma unroll
            for (int r = 0; r < 4; ++r) {
                float s = rsum[mi][r];
                s += __shfl_xor(s, 1); s += __shfl_xor(s, 2);
                s += __shfl_xor(s, 4); s += __shfl_xor(s, 8);
                if ((l & 15) == 0)
                    srp[((size_t)(z << 4) + (colstrip << 2) + wc) * BROWS +
                        arow0 + (wr << 6) + (mi << 4) + ((l >> 4) << 2) + r] = s;
            }
    }
}

// ---- fold partial strips into sums[4][BROWS] ----
__global__ __launch_bounds__(256) void reduce_sums(const float* __restrict__ srp,
                                                   const float* __restrict__ scp,
                                                   float* __restrict__ sums) {
    const int idx = blockIdx.x * 256 + threadIdx.x;   // 8192
    const int z = idx >> 12, row = idx & 4095;
    float a = 0.f, b = 0.f;
#pragma unroll 4
    for (int s = 0; s < 16; ++s) a += srp[((size_t)(z << 4) + s) * BROWS + row];
#pragma unroll 4
    for (int s = 0; s < 64; ++s) b += scp[((size_t)(z << 6) + s) * BROWS + row];
    sums[(size_t)(2 * z) * BROWS + row] = a;
    sums[(size_t)(2 * z + 1) * BROWS + row] = b;
}

// ---- gather nn rows: 8 rows/block-iter, 16B/lane ----
__global__ __launch_bounds__(256) void gather_bf(const u64_t* __restrict__ packed,
                                                 const ushort_t* __restrict__ qb,
                                                 ushort_t* __restrict__ nn) {
    const int r8 = threadIdx.x >> 5;   // 0..7
    const int c = threadIdx.x & 31;    // 32 chunks of 8 ushorts
    for (int base = blockIdx.x * 8; base < 2 * BROWS; base += (int)gridDim.x * 8) {
        const int i = base + r8;
        const unsigned idx = 0xFFFFFFFFu - (unsigned)(packed[i] & 0xFFFFFFFFull);
        *(v8us*)&nn[(size_t)i * DIMK + (c << 3)] =
            *(const v8us*)&qb[(size_t)idx * DIMK + (c << 3)];
    }
}

__global__ __launch_bounds__(256) void final_loss(const float* __restrict__ d1,
                                                  const float* __restrict__ d2,
                                                  const float* __restrict__ sr1,
                                                  const float* __restrict__ sc1,
                                                  const float* __restrict__ sr2,
                                                  const float* __restrict__ sc2,
                                                  float* __restrict__ out) {
    __shared__ float red[256];
    const int t = threadIdx.x;
    float acc = 0.f;
    for (int i = t; i < BROWS; i += 256) {
        acc += 2.f * (d1[i] + d2[i]) - logf(sr1[i]) - logf(sc1[i]) - logf(sr2[i]) - logf(sc2[i]);
    }
    red[t] = acc;
    __syncthreads();
    for (int s = 128; s > 0; s >>= 1) {
        if (t < s) red[t] += red[t + s];
        __syncthreads();
    }
    if (t == 0) out[0] = -red[0] / (4.0f * (float)BROWS);
}

extern "C" void kernel_launch(void* const* d_in, const int* in_sizes, int n_in,
                              void* d_out, int out_size, void* d_ws, size_t ws_size,
                              hipStream_t stream) {
    const float* f1 = (const float*)d_in[0];
    const float* f2 = (const float*)d_in[1];
    const float* W1 = (const float*)d_in[2];
    const float* b1 = (const float*)d_in[3];
    const float* W2 = (const float*)d_in[4];
    const float* b2 = (const float*)d_in[5];
    const float* queue = (const float*)d_in[6];
    float* out = (float*)d_out;

    char* ws = (char*)d_ws;
    ushort_t* pcat  = (ushort_t*)(ws + (8ull << 20));      // 4 MB: p1 | p2
    ushort_t* nncat = (ushort_t*)(ws + (12ull << 20));     // 4 MB: nn1 | nn2
    ushort_t* qb    = (ushort_t*)(ws + (16ull << 20));     // 16 MB
    u64_t* packed   = (u64_t*)(ws + (32ull << 20));        // 64 KB (8192 rows)
    float* sums     = (float*)(ws + (32ull << 20) + (64ull << 10));    // 64 KB
    float* diag     = (float*)(ws + (32ull << 20) + (128ull << 10));   // 32 KB
    float* srp      = (float*)(ws + (32ull << 20) + (160ull << 10));   // 512 KB
    float* scp      = (float*)(ws + (32ull << 20) + (672ull << 10));   // 2 MB

    hipMemsetAsync(packed, 0, (64ull << 10), stream);

    conv_bf16<<<(QN * DIMK) / 2048, 256, 0, stream>>>(queue, qb);

    dim3 gp(BROWS / 16, 2);
    proj_fused<<<gp, 256, 0, stream>>>(f1, f2, W1, b1, W2, b2, pcat);

    nn_lse<0, 16><<<256, 512, 0, stream>>>(pcat, qb, packed, nullptr, nullptr, nullptr);

    gather_bf<<<256, 256, 0, stream>>>(packed, qb, nncat);

    nn_lse<1, 2><<<256, 512, 0, stream>>>(nncat, pcat, nullptr, srp, scp, diag);

    reduce_sums<<<32, 256, 0, stream>>>(srp, scp, sums);

    final_loss<<<1, 256, 0, stream>>>(diag, diag + BROWS,
                                      sums, sums + BROWS, sums + 2 * BROWS, sums + 3 * BROWS,
                                      out);
}